// Round 2
// 1864.650 us; speedup vs baseline: 2.0186x; 2.0186x over previous
//
#include <hip/hip_runtime.h>
#include <hip/hip_bf16.h>

// Problem constants (from reference)
#define E_N    800000
#define NODES  50000
#define NC     128     // node channels
#define EC     64      // edge channels
#define K1     320     // 2*NC + EC  (edge MLP layer-1 fan-in)
#define H1     128     // edge MLP hidden
#define O2E    64      // edge MLP out
#define NK1    192     // NC + EC    (node MLP layer-1 fan-in)

// ---------- helpers ----------
__device__ __forceinline__ float2 bfp2f(unsigned int p) {
    union { unsigned int i; float f; } lo, hi;
    lo.i = p << 16; hi.i = p & 0xffff0000u;
    float2 r; r.x = lo.f; r.y = hi.f; return r;
}
__device__ __forceinline__ unsigned short f2bf(float f) {
    union { float ff; unsigned int i; } v; v.ff = f;
    unsigned int x = v.i;
    return (unsigned short)((x + 0x7fffu + ((x >> 16) & 1u)) >> 16);
}
__device__ __forceinline__ unsigned int packbf(float a, float b) {
    return (unsigned int)f2bf(a) | ((unsigned int)f2bf(b) << 16);
}
__device__ __forceinline__ float bf2f(unsigned short u) {
    union { unsigned int i; float f; } v; v.i = ((unsigned int)u) << 16; return v.f;
}
__device__ __forceinline__ float silu_f(float x) { return x / (1.0f + __expf(-x)); }

// =====================================================================
// Precompute kernel: per node v
//   PA[v][c] = xn[v] @ W1a[:,c] + eb1[c]      (rows   0..127 of eW1)
//   PB[v][c] = xn[v] @ W1b[:,c]               (rows 128..255 of eW1)
// Stored as bf16 in the out_n region (overwritten later by node_kernel).
// Thread layout (256): col = t&127, half = t>>7 (0 -> PA, 1 -> PB).
// fp32 weights resident in registers (128 VGPRs).
// =====================================================================
__global__ __launch_bounds__(256, 2) void pre_kernel(
    const float* __restrict__ xn,
    const float* __restrict__ eW1,
    const float* __restrict__ eb1,
    unsigned short* __restrict__ pa,   // [NODES,128] bf16
    unsigned short* __restrict__ pb)   // [NODES,128] bf16
{
    const int t    = threadIdx.x;
    const int col  = t & 127;
    const int half = t >> 7;          // 0: W1a (+bias) ; 1: W1b
    const int row0 = half * NC;       // 0 or 128

    float w[128];
    #pragma unroll
    for (int k = 0; k < 128; ++k)
        w[k] = eW1[(size_t)(row0 + k) * H1 + col];
    const float bias = half ? 0.0f : eb1[col];

    __shared__ float4 sx[NC / 4];   // 32 float4 = xn row

    unsigned short* __restrict__ dst = half ? pb : pa;

    for (int v = blockIdx.x; v < NODES; v += gridDim.x) {
        if (t < 32) sx[t] = ((const float4*)(xn + (size_t)v * NC))[t];
        __syncthreads();

        float a0 = 0.f, a1 = 0.f, a2 = 0.f, a3 = 0.f;
        #pragma unroll
        for (int j = 0; j < 32; ++j) {
            float4 x = sx[j];
            a0 = fmaf(w[4 * j + 0], x.x, a0);
            a1 = fmaf(w[4 * j + 1], x.y, a1);
            a2 = fmaf(w[4 * j + 2], x.z, a2);
            a3 = fmaf(w[4 * j + 3], x.w, a3);
        }
        float r = (a0 + a1) + (a2 + a3) + bias;
        dst[(size_t)v * NC + col] = f2bf(r);
        __syncthreads();   // protect sx before next staging
    }
}

// =====================================================================
// Edge kernel (factorized): per edge e
//   h[c]  = silu(PA[snd][c] + PB[rcv][c] + xe[e] @ W1c[:,c])   (b1 in PA)
//   o[j]  = silu(h @ W2[:,j] + b2[j])
//   out_e[e] = o;  aggr[rcv] += o (fp32 atomics)
// Block of 256 processes TWO edges per iteration:
//   sub = t>>7 (which edge), c = t&127 (GEMM1 channel),
//   o = t&63, q = (t>>6)&1 (GEMM2 K-half).
// fp32 weights in registers: W1c col (64) + W2 half-col (64) = 128 VGPRs.
// 3 barriers per 2 edges (vs 4 per edge before).
// =====================================================================
__global__ __launch_bounds__(256, 2) void edge_kernel(
    const float* __restrict__ xe,
    const int* __restrict__ ei,
    const unsigned short* __restrict__ pa,   // [NODES,128] bf16 (incl. b1)
    const unsigned short* __restrict__ pb,   // [NODES,128] bf16
    const float* __restrict__ eW1,           // W1c = rows 256..319
    const float* __restrict__ eW2,
    const float* __restrict__ eb2,
    float* __restrict__ out_e,               // [E_N, 64] f32
    float* __restrict__ aggr)                // [NODES, 64] f32 (pre-zeroed)
{
    const int t   = threadIdx.x;
    const int sub = t >> 7;         // which of the two edges
    const int c   = t & 127;        // GEMM1 output channel
    const int o   = t & 63;         // GEMM2 output channel
    const int q   = (t >> 6) & 1;   // GEMM2 K-half

    // --- register-resident fp32 weights ---
    float w1[64];                    // W1c[:, c]
    #pragma unroll
    for (int k = 0; k < 64; ++k)
        w1[k] = eW1[(size_t)(256 + k) * H1 + c];
    float w2[64];                    // W2[q*64 .. q*64+63, o]
    #pragma unroll
    for (int k = 0; k < 64; ++k)
        w2[k] = eW2[(size_t)(q * 64 + k) * O2E + o];
    const float b2v = eb2[o];

    __shared__ float4 xbuf[2][EC / 4];   // 2 x 64 f32  (xe rows)
    __shared__ float4 hbuf[2][H1 / 4];   // 2 x 128 f32 (hidden)
    __shared__ float  red[2][O2E];       // GEMM2 cross-half reduce

    for (int base = blockIdx.x * 2; base < E_N; base += gridDim.x * 2) {
        const int e   = base + sub;          // E_N even -> always in range
        const int snd = ei[e];
        const int rcv = ei[E_N + e];

        // gathered bf16 partial rows (coalesced 2B loads, L2/L3-resident)
        const float pav = bf2f(pa[(size_t)snd * NC + c]);
        const float pbv = bf2f(pb[(size_t)rcv * NC + c]);

        // stage this edge's xe row (16 float4 per edge)
        if (c < 16)
            xbuf[sub][c] = ((const float4*)(xe + (size_t)e * EC))[c];
        __syncthreads();   // B1: xbuf ready

        // ---- GEMM1: 64 MACs, broadcast float4 LDS reads ----
        float a0 = 0.f, a1 = 0.f, a2 = 0.f, a3 = 0.f;
        {
            const float4* xp = xbuf[sub];
            #pragma unroll
            for (int j = 0; j < 16; ++j) {
                float4 x = xp[j];
                a0 = fmaf(w1[4 * j + 0], x.x, a0);
                a1 = fmaf(w1[4 * j + 1], x.y, a1);
                a2 = fmaf(w1[4 * j + 2], x.z, a2);
                a3 = fmaf(w1[4 * j + 3], x.w, a3);
            }
        }
        float h = silu_f((a0 + a1) + (a2 + a3) + pav + pbv);
        ((float*)hbuf[sub])[c] = h;
        __syncthreads();   // B2: hbuf ready

        // ---- GEMM2: 64 MACs over this thread's K-half ----
        float d0 = 0.f, d1 = 0.f, d2 = 0.f, d3 = 0.f;
        {
            const float4* hp = &hbuf[sub][q * 16];
            #pragma unroll
            for (int j = 0; j < 16; ++j) {
                float4 x = hp[j];
                d0 = fmaf(w2[4 * j + 0], x.x, d0);
                d1 = fmaf(w2[4 * j + 1], x.y, d1);
                d2 = fmaf(w2[4 * j + 2], x.z, d2);
                d3 = fmaf(w2[4 * j + 3], x.w, d3);
            }
        }
        float acc2 = (d0 + d1) + (d2 + d3);
        if (q) red[sub][o] = acc2;
        __syncthreads();   // B3: red ready
        if (!q) {
            float ov = silu_f(acc2 + red[sub][o] + b2v);
            out_e[(size_t)e * O2E + o] = ov;
            unsafeAtomicAdd(&aggr[(size_t)rcv * O2E + o], ov);
        }
        // No trailing barrier needed:
        //  - xbuf: last read pre-B2; next write post-B3 but pre-B1'.
        //  - hbuf: last read pre-B3; next write post-B1'.
        //  - red : last read post-B3; next write post-B2'.
    }
}

// =====================================================================
// Node kernel (unchanged): per node v
//   n[192]   = concat(xn[v], aggr[v])
//   h[128]   = silu(n @ nW1 + nb1)
//   out[128] = h @ nW2 + nb2          (no final silu)
// =====================================================================
__global__ __launch_bounds__(256, 2) void node_kernel(
    const float* __restrict__ xn,
    const float* __restrict__ aggr,
    const float* __restrict__ nW1, const float* __restrict__ nb1,
    const float* __restrict__ nW2, const float* __restrict__ nb2,
    float* __restrict__ out_n)   // [NODES, 128] f32
{
    const int t  = threadIdx.x;
    const int c  = t & 127;
    const int kh = t >> 7;   // 0/1

    unsigned int w1[48];
    {
        const int k0 = kh * 96;
        #pragma unroll
        for (int j = 0; j < 48; ++j) {
            float lo = nW1[(size_t)(k0 + 2 * j) * NC + c];
            float hi = nW1[(size_t)(k0 + 2 * j + 1) * NC + c];
            w1[j] = packbf(lo, hi);
        }
    }
    unsigned int w2[32];
    {
        const int k0 = kh * 64;
        #pragma unroll
        for (int j = 0; j < 32; ++j) {
            float lo = nW2[(size_t)(k0 + 2 * j) * NC + c];
            float hi = nW2[(size_t)(k0 + 2 * j + 1) * NC + c];
            w2[j] = packbf(lo, hi);
        }
    }
    const float b1 = nb1[c];
    const float b2 = nb2[c];

    __shared__ float4 sbuf4[NK1 / 4];  // 192 f32
    __shared__ float  red1[NC];
    __shared__ float2 hbuf[NC / 2];    // 128 f32

    for (int v = blockIdx.x; v < NODES; v += gridDim.x) {
        {
            const float4* n_row = (const float4*)(xn + (size_t)v * NC);    // 32 float4
            const float4* a_row = (const float4*)(aggr + (size_t)v * EC);  // 16 float4
            if (t < 32)       sbuf4[t] = n_row[t];        // k   0..127
            else if (t < 48)  sbuf4[t] = a_row[t - 32];   // k 128..191
        }
        __syncthreads();

        float acc = 0.f;
        {
            const float2* sp = ((const float2*)sbuf4) + kh * 48;
            #pragma unroll
            for (int j = 0; j < 48; ++j) {
                float2 wv = bfp2f(w1[j]);
                float2 sv = sp[j];
                acc += wv.x * sv.x;
                acc += wv.y * sv.y;
            }
        }
        if (kh == 1) red1[c] = acc;
        __syncthreads();
        if (kh == 0) {
            float h = silu_f(acc + red1[c] + b1);
            ((float*)hbuf)[c] = h;
        }
        __syncthreads();

        float acc2 = 0.f;
        {
            const float2* hp = hbuf + kh * 32;
            #pragma unroll
            for (int j = 0; j < 32; ++j) {
                float2 wv = bfp2f(w2[j]);
                float2 hv = hp[j];
                acc2 += wv.x * hv.x;
                acc2 += wv.y * hv.y;
            }
        }
        if (kh == 1) red1[c] = acc2;
        __syncthreads();
        if (kh == 0) {
            float o = acc2 + red1[c] + b2;
            out_n[(size_t)v * NC + c] = o;
        }
        __syncthreads();
    }
}

extern "C" void kernel_launch(void* const* d_in, const int* in_sizes, int n_in,
                              void* d_out, int out_size, void* d_ws, size_t ws_size,
                              hipStream_t stream) {
    const float* xn  = (const float*)d_in[0];   // [50000,128] f32
    const float* xe  = (const float*)d_in[1];   // [800000,64] f32
    const int*   ei  = (const int*)d_in[2];     // [2,800000] int32
    const float* eW1 = (const float*)d_in[3];   // [320,128]
    const float* eb1 = (const float*)d_in[4];   // [128]
    const float* eW2 = (const float*)d_in[5];   // [128,64]
    const float* eb2 = (const float*)d_in[6];   // [64]
    const float* nW1 = (const float*)d_in[7];   // [192,128]
    const float* nb1 = (const float*)d_in[8];   // [128]
    const float* nW2 = (const float*)d_in[9];   // [128,128]
    const float* nb2 = (const float*)d_in[10];  // [128]

    float* out_n = (float*)d_out;               // [50000,128] f32
    float* out_e = out_n + (size_t)NODES * NC;  // [800000,64] f32
    float* aggr  = (float*)d_ws;                // [50000,64] f32

    // PA/PB (bf16) live in the out_n region (25.6 MB exactly); node_kernel
    // overwrites it at the very end, after edge_kernel has consumed them.
    unsigned short* pa = (unsigned short*)out_n;         // [NODES,128] bf16
    unsigned short* pb = pa + (size_t)NODES * NC;        // [NODES,128] bf16

    // zero the scatter accumulator (ws is re-poisoned before every launch)
    hipMemsetAsync(aggr, 0, (size_t)NODES * O2E * sizeof(float), stream);

    hipLaunchKernelGGL(pre_kernel, dim3(1024), dim3(256), 0, stream,
                       xn, eW1, eb1, pa, pb);
    hipLaunchKernelGGL(edge_kernel, dim3(1024), dim3(256), 0, stream,
                       xe, ei, pa, pb, eW1, eW2, eb2, out_e, aggr);
    hipLaunchKernelGGL(node_kernel, dim3(1024), dim3(256), 0, stream,
                       xn, aggr, nW1, nb1, nW2, nb2, out_n);
}

// Round 4
// 1011.422 us; speedup vs baseline: 3.7215x; 1.8436x over previous
//
#include <hip/hip_runtime.h>
#include <hip/hip_bf16.h>

// Problem constants (from reference)
#define E_N    800000
#define NODES  50000
#define NC     128     // node channels
#define EC     64      // edge channels
#define H1     128     // edge MLP hidden
#define O2E    64      // edge MLP out
#define NK1    192     // NC + EC    (node MLP layer-1 fan-in)

// clang's AMDGPU builtins use __fp16 ext-vectors (type code V2h)
typedef __fp16 half2_t __attribute__((ext_vector_type(2)));

// ---------- helpers ----------
__device__ __forceinline__ unsigned short f2h_rne(float f) {
    union { _Float16 h; unsigned short s; } v; v.h = (_Float16)f; return v.s;
}
__device__ __forceinline__ float h2f(unsigned short s) {
    union { unsigned short s; _Float16 h; } v; v.s = s; return (float)v.h;
}
// pack two f32 -> packed f16 pair (RNE, init-time / precision-critical)
__device__ __forceinline__ unsigned int packh2(float a, float b) {
    return (unsigned int)f2h_rne(a) | ((unsigned int)f2h_rne(b) << 16);
}
// pack two f32 -> packed f16 pair (RTZ, fast path for activations)
__device__ __forceinline__ unsigned int pkrtz(float a, float b) {
    union { half2_t h; unsigned int u; } v;
    v.h = __builtin_amdgcn_cvt_pkrtz(a, b);
    return v.u;
}
__device__ __forceinline__ half2_t u2h2(unsigned int u) {
    union { unsigned int u; half2_t h; } v; v.u = u; return v.h;
}
// dot2: acc += a.lo*b.lo + a.hi*b.hi  (f32 accumulate, v_dot2_f32_f16)
#define FDOT2(a, b, c) __builtin_amdgcn_fdot2(u2h2(a), u2h2(b), (c), false)

__device__ __forceinline__ float silu_f(float x) { return x / (1.0f + __expf(-x)); }

// =====================================================================
// Precompute kernel: per node v
//   PA[v][c] = xn[v] @ W1a[:,c] + eb1[c]      (rows   0..127 of eW1)
//   PB[v][c] = xn[v] @ W1b[:,c]               (rows 128..255 of eW1)
// Stored as f16 (RNE) in the out_n region (overwritten by node_kernel).
// fp32 weights in regs; fp32 MACs; prefetched staging.
// =====================================================================
__global__ __launch_bounds__(256, 2) void pre_kernel(
    const float* __restrict__ xn,
    const float* __restrict__ eW1,
    const float* __restrict__ eb1,
    unsigned short* __restrict__ pa,   // [NODES,128] f16
    unsigned short* __restrict__ pb)   // [NODES,128] f16
{
    const int t    = threadIdx.x;
    const int col  = t & 127;
    const int half = t >> 7;          // 0: W1a (+bias) ; 1: W1b
    const int row0 = half * NC;       // 0 or 128

    float w[128];
    #pragma unroll
    for (int k = 0; k < 128; ++k)
        w[k] = eW1[(size_t)(row0 + k) * H1 + col];
    const float bias = half ? 0.0f : eb1[col];

    __shared__ __align__(16) float4 sx[NC / 4];   // 32 float4 = xn row

    unsigned short* __restrict__ dst = half ? pb : pa;

    // prologue: prefetch first row
    float4 x4a = make_float4(0.f, 0.f, 0.f, 0.f);
    if (t < 32) x4a = ((const float4*)(xn + (size_t)blockIdx.x * NC))[t];

    for (int v = blockIdx.x; v < NODES; v += gridDim.x) {
        const int vn    = v + gridDim.x;
        const int vload = (vn < NODES) ? vn : v;
        if (t < 32) {
            sx[t] = x4a;                                              // arrived
            x4a = ((const float4*)(xn + (size_t)vload * NC))[t];      // issue next
        }
        __syncthreads();

        float a0 = 0.f, a1 = 0.f, a2 = 0.f, a3 = 0.f;
        #pragma unroll
        for (int j = 0; j < 32; ++j) {
            float4 x = sx[j];
            a0 = fmaf(w[4 * j + 0], x.x, a0);
            a1 = fmaf(w[4 * j + 1], x.y, a1);
            a2 = fmaf(w[4 * j + 2], x.z, a2);
            a3 = fmaf(w[4 * j + 3], x.w, a3);
        }
        float r = (a0 + a1) + (a2 + a3) + bias;
        dst[(size_t)v * NC + col] = f2h_rne(r);
        __syncthreads();   // protect sx before next iteration's write
    }
}

// =====================================================================
// Edge kernel (factorized, f16-dot2, software-pipelined): per edge e
//   h[c]  = silu(PA[snd][c] + PB[rcv][c] + xe[e] @ W1c[:,c])   (b1 in PA)
//   o[j]  = silu(h @ W2[:,j] + b2[j])
//   out_e[e] = o;  aggr[rcv] += o (fp32 atomics)
// 256 threads process TWO edges per iteration:
//   sub = t>>7, c = t&127 (GEMM1 channel), o = t&63, q = (t>>6)&1.
// Weights: packed f16 pairs, 64 VGPRs total. GEMMs via v_dot2_f32_f16.
// Pipeline: ei/xe for iter t+1 issued at top of t; pa/pb for t+1 issued
// mid-t (after ei lands); consumed at t+1. Single-buffer LDS (each
// write->read window separated from next write by >=2 barriers).
// =====================================================================
__global__ __launch_bounds__(256, 4) void edge_kernel(
    const float* __restrict__ xe,
    const int* __restrict__ ei,
    const unsigned short* __restrict__ pa,   // [NODES,128] f16 (incl. b1)
    const unsigned short* __restrict__ pb,   // [NODES,128] f16
    const float* __restrict__ eW1,           // W1c = rows 256..319
    const float* __restrict__ eW2,
    const float* __restrict__ eb2,
    float* __restrict__ out_e,               // [E_N, 64] f32
    float* __restrict__ aggr)                // [NODES, 64] f32 (pre-zeroed)
{
    const int t   = threadIdx.x;
    const int sub = t >> 7;         // which of the two edges
    const int c   = t & 127;        // GEMM1 output channel
    const int o   = t & 63;         // GEMM2 output channel
    const int q   = (t >> 6) & 1;   // GEMM2 K-half

    // --- packed f16 weights in registers (64 VGPRs) ---
    unsigned int w1p[32];            // W1c[:, c] pairs
    #pragma unroll
    for (int j = 0; j < 32; ++j)
        w1p[j] = packh2(eW1[(size_t)(256 + 2 * j) * H1 + c],
                        eW1[(size_t)(256 + 2 * j + 1) * H1 + c]);
    unsigned int w2p[32];            // W2[q*64 .., o] pairs
    #pragma unroll
    for (int j = 0; j < 32; ++j)
        w2p[j] = packh2(eW2[(size_t)(q * 64 + 2 * j) * O2E + o],
                        eW2[(size_t)(q * 64 + 2 * j + 1) * O2E + o]);
    const float b2v = eb2[o];

    __shared__ __align__(16) uint2        xbufp[2][16];  // per sub: 64 f16 (xe row)
    __shared__ __align__(16) unsigned int hbufp[2][64];  // per sub: 128 f16 (hidden)
    __shared__ float                      red[2][O2E];   // GEMM2 cross-half reduce

    const int stride = gridDim.x * 2;

    // ---- prologue: load iter-0 state ----
    int rcv_c;
    unsigned short pav_c, pbv_c;
    float4 x4 = make_float4(0.f, 0.f, 0.f, 0.f);
    {
        const int e0  = blockIdx.x * 2 + sub;     // < 2048 < E_N
        const int snd = ei[e0];
        rcv_c = ei[E_N + e0];
        pav_c = pa[(size_t)snd * NC + c];
        pbv_c = pb[(size_t)rcv_c * NC + c];
        if (c < 16) x4 = ((const float4*)(xe + (size_t)e0 * EC))[c];
    }

    for (int base = blockIdx.x * 2; base < E_N; base += stride) {
        const int e_cur   = base + sub;
        const int rcv_cur = rcv_c;
        const unsigned short pav = pav_c, pbv = pbv_c;

        const int basen = base + stride;
        const int en    = (basen < E_N) ? (basen + sub) : e_cur;  // safe clamp

        // stage current xe tile (x4 arrived one iteration ago)
        if (c < 16)
            xbufp[sub][c] = make_uint2(pkrtz(x4.x, x4.y), pkrtz(x4.z, x4.w));
        // issue next ei + xe loads (consumed next iteration)
        const int snd_n = ei[en];
        const int rcv_n = ei[E_N + en];
        if (c < 16) x4 = ((const float4*)(xe + (size_t)en * EC))[c];

        __syncthreads();   // B1: xbufp ready

        // ---- GEMM1: 4 x ds_read_b128 + 32 x v_dot2_f32_f16 ----
        float a0 = 0.f, a1 = 0.f;
        {
            const uint4* xp = (const uint4*)xbufp[sub];
            #pragma unroll
            for (int j = 0; j < 8; ++j) {
                uint4 u = xp[j];
                a0 = FDOT2(u.x, w1p[4 * j + 0], a0);
                a1 = FDOT2(u.y, w1p[4 * j + 1], a1);
                a0 = FDOT2(u.z, w1p[4 * j + 2], a0);
                a1 = FDOT2(u.w, w1p[4 * j + 3], a1);
            }
        }
        float h = silu_f(a0 + a1 + h2f(pav) + h2f(pbv));

        // pack h pairs via lane-exchange; even lane stores the pair
        float hx = __shfl_xor(h, 1);
        unsigned int hpk = (c & 1) ? pkrtz(hx, h) : pkrtz(h, hx);
        if (!(c & 1)) hbufp[sub][c >> 1] = hpk;

        // issue next pa/pb gathers (ei for t+1 has landed by now)
        pav_c = pa[(size_t)snd_n * NC + c];
        pbv_c = pb[(size_t)rcv_n * NC + c];
        rcv_c = rcv_n;

        __syncthreads();   // B2: hbufp ready

        // ---- GEMM2: 2 x ds_read_b128 + 32 x v_dot2_f32_f16 ----
        float d0 = 0.f, d1 = 0.f;
        {
            const uint4* hp4 = ((const uint4*)hbufp[sub]) + q * 8;
            #pragma unroll
            for (int j = 0; j < 8; ++j) {
                uint4 u = hp4[j];
                d0 = FDOT2(u.x, w2p[4 * j + 0], d0);
                d1 = FDOT2(u.y, w2p[4 * j + 1], d1);
                d0 = FDOT2(u.z, w2p[4 * j + 2], d0);
                d1 = FDOT2(u.w, w2p[4 * j + 3], d1);
            }
        }
        float acc2 = d0 + d1;
        if (q) red[sub][o] = acc2;
        __syncthreads();   // B3: red ready
        if (!q) {
            float ov = silu_f(acc2 + red[sub][o] + b2v);
            out_e[(size_t)e_cur * O2E + o] = ov;
            unsafeAtomicAdd(&aggr[(size_t)rcv_cur * O2E + o], ov);
        }
        // LDS race audit (single buffers, no trailing barrier):
        //  xbufp: read pre-B2; next write pre-B1'  -> separated by B2,B3.
        //  hbufp: read pre-B3; next write pre-B2'  -> separated by B3,B1'.
        //  red  : read post-B3; next write pre-B3' -> separated by B1',B2'.
    }
}

// =====================================================================
// Node kernel (f16-dot2, prefetched staging): per node v
//   n[192]   = concat(xn[v], aggr[v])
//   h[128]   = silu(n @ nW1 + nb1)
//   out[128] = h @ nW2 + nb2          (no final silu)
// Thread layout: c = t&127, kh = t>>7 (K-halves).
// =====================================================================
__global__ __launch_bounds__(256, 3) void node_kernel(
    const float* __restrict__ xn,
    const float* __restrict__ aggr,
    const float* __restrict__ nW1, const float* __restrict__ nb1,
    const float* __restrict__ nW2, const float* __restrict__ nb2,
    float* __restrict__ out_n)   // [NODES, 128] f32
{
    const int t  = threadIdx.x;
    const int c  = t & 127;
    const int kh = t >> 7;   // 0/1

    unsigned int w1p[48];    // nW1[kh*96 .., c] pairs
    {
        const int k0 = kh * 96;
        #pragma unroll
        for (int j = 0; j < 48; ++j)
            w1p[j] = packh2(nW1[(size_t)(k0 + 2 * j) * NC + c],
                            nW1[(size_t)(k0 + 2 * j + 1) * NC + c]);
    }
    unsigned int w2p[32];    // nW2[kh*64 .., c] pairs
    {
        const int k0 = kh * 64;
        #pragma unroll
        for (int j = 0; j < 32; ++j)
            w2p[j] = packh2(nW2[(size_t)(k0 + 2 * j) * NC + c],
                            nW2[(size_t)(k0 + 2 * j + 1) * NC + c]);
    }
    const float b1 = nb1[c];
    const float b2 = nb2[c];

    __shared__ __align__(16) uint2        sbufp[48];   // 192 f16 (concat input)
    __shared__ float                      red1[NC];
    __shared__ __align__(16) unsigned int hbufp[64];   // 128 f16 (hidden)

    // prologue: prefetch first row's float4s
    float4 x4a = make_float4(0.f, 0.f, 0.f, 0.f);
    if (t < 32)       x4a = ((const float4*)(xn + (size_t)blockIdx.x * NC))[t];
    else if (t < 48)  x4a = ((const float4*)(aggr + (size_t)blockIdx.x * EC))[t - 32];

    for (int v = blockIdx.x; v < NODES; v += gridDim.x) {
        const int vn    = v + gridDim.x;
        const int vload = (vn < NODES) ? vn : v;

        // stage current row (x4a arrived); issue next row's loads
        if (t < 48) {
            sbufp[t] = make_uint2(pkrtz(x4a.x, x4a.y), pkrtz(x4a.z, x4a.w));
            x4a = (t < 32)
                ? ((const float4*)(xn + (size_t)vload * NC))[t]
                : ((const float4*)(aggr + (size_t)vload * EC))[t - 32];
        }
        __syncthreads();   // B1: sbufp ready

        // ---- GEMM1: 48 dot2 (96 MACs, K-half) ----
        float a0 = 0.f, a1 = 0.f;
        {
            const uint4* sp = ((const uint4*)sbufp) + kh * 12;
            #pragma unroll
            for (int j = 0; j < 12; ++j) {
                uint4 u = sp[j];
                a0 = FDOT2(u.x, w1p[4 * j + 0], a0);
                a1 = FDOT2(u.y, w1p[4 * j + 1], a1);
                a0 = FDOT2(u.z, w1p[4 * j + 2], a0);
                a1 = FDOT2(u.w, w1p[4 * j + 3], a1);
            }
        }
        float acc = a0 + a1;
        if (kh) red1[c] = acc;
        __syncthreads();   // B2: red1 ready

        if (!kh) {
            float h  = silu_f(acc + red1[c] + b1);
            float hx = __shfl_xor(h, 1);
            unsigned int hpk = (c & 1) ? pkrtz(hx, h) : pkrtz(h, hx);
            if (!(c & 1)) hbufp[c >> 1] = hpk;
        }
        __syncthreads();   // B3: hbufp ready

        // ---- GEMM2: 32 dot2 (64 MACs, K-half) ----
        float d0 = 0.f, d1 = 0.f;
        {
            const uint4* hp4 = ((const uint4*)hbufp) + kh * 8;
            #pragma unroll
            for (int j = 0; j < 8; ++j) {
                uint4 u = hp4[j];
                d0 = FDOT2(u.x, w2p[4 * j + 0], d0);
                d1 = FDOT2(u.y, w2p[4 * j + 1], d1);
                d0 = FDOT2(u.z, w2p[4 * j + 2], d0);
                d1 = FDOT2(u.w, w2p[4 * j + 3], d1);
            }
        }
        float acc2 = d0 + d1;
        if (kh) red1[c] = acc2;
        __syncthreads();   // B4: red1 (GEMM2) ready
        if (!kh) out_n[(size_t)v * NC + c] = acc2 + red1[c] + b2;
        // sbufp next write pre-B1' (after B4): reads ended pre-B2. Safe.
        // hbufp next write pre-B3' : reads ended pre-B4. Safe.
        // red1  next write pre-B2' : reads ended post-B4 epilogue, then B1'. Safe.
    }
}

extern "C" void kernel_launch(void* const* d_in, const int* in_sizes, int n_in,
                              void* d_out, int out_size, void* d_ws, size_t ws_size,
                              hipStream_t stream) {
    const float* xn  = (const float*)d_in[0];   // [50000,128] f32
    const float* xe  = (const float*)d_in[1];   // [800000,64] f32
    const int*   ei  = (const int*)d_in[2];     // [2,800000] int32
    const float* eW1 = (const float*)d_in[3];   // [320,128]
    const float* eb1 = (const float*)d_in[4];   // [128]
    const float* eW2 = (const float*)d_in[5];   // [128,64]
    const float* eb2 = (const float*)d_in[6];   // [64]
    const float* nW1 = (const float*)d_in[7];   // [192,128]
    const float* nb1 = (const float*)d_in[8];   // [128]
    const float* nW2 = (const float*)d_in[9];   // [128,128]
    const float* nb2 = (const float*)d_in[10];  // [128]

    float* out_n = (float*)d_out;               // [50000,128] f32
    float* out_e = out_n + (size_t)NODES * NC;  // [800000,64] f32
    float* aggr  = (float*)d_ws;                // [50000,64] f32

    // PA/PB (f16) live in the out_n region (25.6 MB exactly); node_kernel
    // overwrites it at the very end, after edge_kernel has consumed them.
    unsigned short* pa = (unsigned short*)out_n;         // [NODES,128] f16
    unsigned short* pb = pa + (size_t)NODES * NC;        // [NODES,128] f16

    // zero the scatter accumulator (ws is re-poisoned before every launch)
    (void)hipMemsetAsync(aggr, 0, (size_t)NODES * O2E * sizeof(float), stream);

    hipLaunchKernelGGL(pre_kernel, dim3(1024), dim3(256), 0, stream,
                       xn, eW1, eb1, pa, pb);
    hipLaunchKernelGGL(edge_kernel, dim3(1024), dim3(256), 0, stream,
                       xe, ei, pa, pb, eW1, eW2, eb2, out_e, aggr);
    hipLaunchKernelGGL(node_kernel, dim3(1024), dim3(256), 0, stream,
                       xn, aggr, nW1, nb1, nW2, nb2, out_n);
}